// Round 14
// baseline (510.891 us; speedup 1.0000x reference)
//
#include <hip/hip_runtime.h>
#include <hip/hip_bf16.h>
#include <math.h>

// Problem constants
#define M_ 2048
#define K_ 1024
#define V_ 50000
#define VP_ 50048        // V padded to 128
#define CV_ 120
#define NC_ (V_ + CV_)   // 50120 out row stride
#define S_ 100
#define B_ 32
#define PAD_IDX_ 1

// GEMM tiling: block 256x128, 4 waves stacked in M, wave tile 64x128
// fp8 e4m3 operands, BK=64 (64 BYTES per row)
#define BM 256
#define BN 128
#define BK 64
#define NKT (K_ / BK)                   // 16 k-steps
#define NB_ (VP_ / BN)                  // 391 N-blocks
#define NMT (M_ / BM)                   // 8 M-blocks
#define NWG_ (NMT * NB_)                // 3128 = 8 * 391
#define WPX_ (NWG_ / 8)                 // 391 (exact)
#define BUFB 24576                      // BYTES per pipeline buf (A 16KB + B 8KB)
#define ELSB 136                        // Els row stride (BYTES)
#define PLSS 36                         // Pls row stride (floats)
#define WEPI 17920                      // per-wave epilogue LDS slab
#define LN16 2.772588722239781f         // E stored as e/16 == exp(logit - ln16)

// merged pre-kernel block ranges
#define WT_BLKS (782 * 16)              // 12512 (64v x 64k tiles)
#define PREP_BLKS (M_ / 4)              // 512
#define IDS_BLKS (((S_ * B_) + 255) / 256) // 13

typedef float f32x2 __attribute__((ext_vector_type(2)));
typedef float f32x4 __attribute__((ext_vector_type(4)));
typedef float f32x16 __attribute__((ext_vector_type(16)));
typedef int i32x4 __attribute__((ext_vector_type(4)));
typedef int i32x8 __attribute__((ext_vector_type(8)));
typedef unsigned int u32x2 __attribute__((ext_vector_type(2)));
typedef unsigned short ushort;
typedef unsigned char u8;

__device__ __forceinline__ void async_copy16(const void* g, void* l) {
    __builtin_amdgcn_global_load_lds(
        (const __attribute__((address_space(1))) void*)g,
        (__attribute__((address_space(3))) void*)l, 16, 0, 0);
}
// quarter-wave conflict-free chunk swizzle (verified r4: conflicts -> 0)
#define SIG(row) (((row) >> 1) & 3)

// ---------------------------------------------------------------------------
// merged pre-pass: [0,WT_BLKS) W-transpose->fp8; [WT,+PREP) hidden->fp8 +
// copy gate; [+PREP,+IDS) one-hot -> ids.
__global__ __launch_bounds__(256)
void k_pre(const float* __restrict__ W, u8* __restrict__ Wt,
           const float* __restrict__ hidden, const float* __restrict__ w_copy,
           const float* __restrict__ b_copy, u8* __restrict__ Ab,
           float* __restrict__ cvec, const float* __restrict__ src_map,
           int* __restrict__ ids)
{
    int bx = blockIdx.x;
    int tid = threadIdx.x;
    if (bx < WT_BLKS) {
        // ---- W [K][V] fp32 -> Wt [VP][K] fp8 (64x64 tile transpose)
        __shared__ __align__(16) u8 t8[64][80];
        int v0 = (bx % 782) * 64;
        int k0 = (bx / 782) * 64;
        int kr = tid >> 4;          // 0..15
        int vq = tid & 15;
        int v4 = v0 + vq * 4;
#pragma unroll
        for (int i = 0; i < 4; ++i) {
            int k = k0 + kr + i * 16;
            f32x4 val = {};
            if (v4 < V_) val = *(const f32x4*)(W + (size_t)k * V_ + v4);
#pragma unroll
            for (int c = 0; c < 4; ++c) {
                int r = __builtin_amdgcn_cvt_pk_fp8_f32(val[c], 0.f, 0, 0);
                t8[vq * 4 + c][kr + i * 16] = (u8)r;
            }
        }
        __syncthreads();
        int vr = tid >> 2;          // 0..63
        int q  = tid & 3;           // 16B chunk of the 64B k-run
        i32x4 o = *(const i32x4*)(&t8[vr][q * 16]);
        *(i32x4*)(Wt + (size_t)(v0 + vr) * K_ + k0 + q * 16) = o;
    } else if (bx < WT_BLKS + PREP_BLKS) {
        // ---- hidden->fp8 + copy gate. 1 wave per row.
        int n = (bx - WT_BLKS) * 4 + (tid >> 6);
        int lane = tid & 63;
        const float* h = hidden + (size_t)n * K_;
        u8* arow = Ab + (size_t)n * K_;
        float s = 0.f;
#pragma unroll
        for (int g = 0; g < 2; ++g) {
            int gg = 2 * lane + g;            // granule 0..127 (8 elems)
            f32x4 a = *(const f32x4*)(h + gg * 8);
            f32x4 b = *(const f32x4*)(h + gg * 8 + 4);
            f32x4 wa = *(const f32x4*)(w_copy + gg * 8);
            f32x4 wb = *(const f32x4*)(w_copy + gg * 8 + 4);
            s += a[0]*wa[0] + a[1]*wa[1] + a[2]*wa[2] + a[3]*wa[3]
               + b[0]*wb[0] + b[1]*wb[1] + b[2]*wb[2] + b[3]*wb[3];
            int p0 = __builtin_amdgcn_cvt_pk_fp8_f32(a[0], a[1], 0, 0);
            p0 = __builtin_amdgcn_cvt_pk_fp8_f32(a[2], a[3], p0, 1);
            int p1 = __builtin_amdgcn_cvt_pk_fp8_f32(b[0], b[1], 0, 0);
            p1 = __builtin_amdgcn_cvt_pk_fp8_f32(b[2], b[3], p1, 1);
            u32x2 pk; pk[0] = (unsigned)p0; pk[1] = (unsigned)p1;
            *(u32x2*)(arow + gg * 8) = pk;
        }
#pragma unroll
        for (int off = 32; off; off >>= 1) s += __shfl_down(s, off);
        if (lane == 0) cvec[n] = 1.f / (1.f + __expf(-(s + b_copy[0])));
    } else {
        // ---- one-hot src_map -> integer ids [S*B]
        int i = (bx - WT_BLKS - PREP_BLKS) * 256 + tid;
        if (i < S_ * B_) {
            const float* r = src_map + (size_t)i * CV_;
            int id = 0;
            for (int v = 0; v < CV_; ++v)
                if (r[v] > 0.5f) { id = v; break; }
            ids[i] = id;
        }
    }
}

// ---------------------------------------------------------------------------
// GEMM (MX-fp8): e' = exp(A.Wt^T + b - ln16) (PAD col->0); fp8 E store;
// coalesced row partials. 3-buf staging + FRAGMENT double-buffer: read step
// kt+1's fragments during kt's MFMAs (LDS pipe overlaps matrix pipe).
template<bool E8P>
__global__ __launch_bounds__(256, 2)
void k_gemm_exp(const u8* __restrict__ A, const u8* __restrict__ Bt,
                const float* __restrict__ bias, float* __restrict__ out,
                u8* __restrict__ E8, float* __restrict__ part2)
{
    __shared__ __align__(16) u8 lds8[3 * BUFB];   // 72 KB

    const int tid  = threadIdx.x;
    const int lane = tid & 63;
    const int wid  = tid >> 6;

    // bijective XCD swizzle: 3128 = 8 * 391
    int orig = blockIdx.y * NMT + blockIdx.x;
    int nid  = (orig & 7) * WPX_ + (orig >> 3);
    const int m0 = (nid & 7) * BM;    // m fastest within an XCD's chunk
    const int nb = nid >> 3;
    const int n0 = nb * BN;

    f32x16 acc[2][4] = {};

    // A tile: 256 rows x 64B = 1024 granules (j 0..3); B: 128 rows = 512 (j 0..1)
#define STAGE_A(d, kt)                                                        \
    do {                                                                      \
        _Pragma("unroll")                                                     \
        for (int j = 0; j < 4; ++j) {                                         \
            int g = j * 256 + tid; int row = g >> 2;                          \
            int ch = (g & 3) ^ SIG(row);                                      \
            async_copy16(A + (size_t)(m0 + row) * K_ + (kt) * BK + ch * 16,   \
                         &lds8[(d) * BUFB + (j * 256 + wid * 64) * 16]);      \
        }                                                                     \
    } while (0)
#define STAGE_B(d, kt)                                                        \
    do {                                                                      \
        _Pragma("unroll")                                                     \
        for (int j = 0; j < 2; ++j) {                                         \
            int g = j * 256 + tid; int row = g >> 2;                          \
            int ch = (g & 3) ^ SIG(row);                                      \
            async_copy16(Bt + (size_t)(n0 + row) * K_ + (kt) * BK + ch * 16,  \
                         &lds8[(d) * BUFB + 16384 + (j * 256 + wid * 64) * 16]); \
        }                                                                     \
    } while (0)

    // 32x32x64 f8f6f4 fragment: row = tile + (lane&31); lane holds 32 k-bytes
    const int rA  = lane & 31;
    const int kb  = lane >> 5;
    const int sig = (rA >> 1) & 3;

    i32x8 fa[2][2], fb[2][4];   // [set][frag] — set = kt&1, static under unroll
#define RDFRAGS(b, s)                                                         \
    do {                                                                      \
        const u8* bufA_ = &lds8[(b) * BUFB];                                  \
        const u8* bufB_ = bufA_ + 16384;                                      \
        _Pragma("unroll")                                                     \
        for (int mt = 0; mt < 2; ++mt) {                                      \
            int ro = (wid * 64 + mt * 32 + rA) * 64;                          \
            i32x4 lo = *(const i32x4*)(bufA_ + ro + (((2*kb+0)^sig) << 4));   \
            i32x4 hi = *(const i32x4*)(bufA_ + ro + (((2*kb+1)^sig) << 4));   \
            fa[s][mt] = __builtin_shufflevector(lo, hi, 0,1,2,3,4,5,6,7);     \
        }                                                                     \
        _Pragma("unroll")                                                     \
        for (int nt = 0; nt < 4; ++nt) {                                      \
            int ro = (nt * 32 + rA) * 64;                                     \
            i32x4 lo = *(const i32x4*)(bufB_ + ro + (((2*kb+0)^sig) << 4));   \
            i32x4 hi = *(const i32x4*)(bufB_ + ro + (((2*kb+1)^sig) << 4));   \
            fb[s][nt] = __builtin_shufflevector(lo, hi, 0,1,2,3,4,5,6,7);     \
        }                                                                     \
    } while (0)

    STAGE_A(0, 0); STAGE_B(0, 0);
    STAGE_A(1, 1); STAGE_B(1, 1);
    asm volatile("s_waitcnt vmcnt(6)" ::: "memory");   // stage 0 landed
    __builtin_amdgcn_s_barrier();
    RDFRAGS(0, 0);                                     // frags for step 0

#pragma unroll
    for (int kt = 0; kt < NKT; ++kt) {
        const int cs = kt & 1, ns = cs ^ 1;
        __builtin_amdgcn_sched_barrier(0);
        asm volatile("s_waitcnt vmcnt(0)" ::: "memory");   // stage kt+1 landed
        __builtin_amdgcn_s_barrier();   // all waves done reading buf (kt-1)%3
        __builtin_amdgcn_sched_barrier(0);
        if (kt < NKT - 2) {
            const int nxt = (kt + 2) % 3;
            STAGE_A(nxt, kt + 2); STAGE_B(nxt, kt + 2);
        }
        if (kt < NKT - 1) RDFRAGS((kt + 1) % 3, ns);   // overlaps MFMAs below
        __builtin_amdgcn_s_setprio(1);
#pragma unroll
        for (int mt = 0; mt < 2; ++mt)
#pragma unroll
            for (int nt = 0; nt < 4; ++nt)
                acc[mt][nt] = __builtin_amdgcn_mfma_scale_f32_32x32x64_f8f6f4(
                    fa[cs][mt], fb[cs][nt], acc[mt][nt], 0, 0, 0, 127, 0, 127);
        __builtin_amdgcn_s_setprio(0);
    }
#undef STAGE_A
#undef STAGE_B
#undef RDFRAGS

    __builtin_amdgcn_s_barrier();   // main loop fully done before LDS reuse

    // epilogue: e' = exp(acc + bias - ln16); fp8-at-write Els staging (bytes),
    // 8-pass coalesced 16B E8 stores, then per-wave Pls reduce.
    // C/D layout (verified m74/m101): col = lane&31, row = (r&3)+8*(r>>2)+4*(lane>>5)
    const int rbase = m0 + wid * 64;
    const int rhi   = (lane >> 5) * 4;
    float psum[2][16];
#pragma unroll
    for (int mt = 0; mt < 2; ++mt)
#pragma unroll
        for (int r = 0; r < 16; ++r) psum[mt][r] = 0.f;
    u8* Els8 = lds8 + wid * WEPI;
    float* Pls = (float*)(lds8 + wid * WEPI + 8704);
#pragma unroll
    for (int nt = 0; nt < 4; ++nt) {
        int gcol = n0 + nt * 32 + rA;
        bool live = (gcol < V_) && (gcol != PAD_IDX_);
        float bln = ((gcol < V_) ? bias[gcol] : 0.f) - LN16;
#pragma unroll
        for (int mt = 0; mt < 2; ++mt) {
#pragma unroll
            for (int r = 0; r < 16; ++r) {
                int crow = (r & 3) + 8 * (r >> 2) + rhi;
                float e = live ? __expf(acc[mt][nt][r] + bln) : 0.f;
                psum[mt][r] += e;
                if (E8P) {
                    Els8[(mt * 32 + crow) * ELSB + nt * 32 + rA] =
                        (u8)__builtin_amdgcn_cvt_pk_fp8_f32(e, 0.f, 0, 0);
                } else {
                    int grow = rbase + mt * 32 + crow;
                    if (gcol < V_) out[(size_t)grow * NC_ + gcol] = e;
                }
            }
        }
    }
    if (E8P) {
        // 8 passes: 8 rows x 128B coalesced segments per pass (cached store)
#pragma unroll
        for (int p = 0; p < 8; ++p) {
            int row_l = p * 8 + (lane >> 3);
            int g = lane & 7;
            i32x4 v = *(const i32x4*)(&Els8[row_l * ELSB + g * 16]);
            *(i32x4*)&E8[(size_t)(rbase + row_l) * VP_ + n0 + g * 16] = v;
        }
    }
    // per-wave Pls transpose reduce (disjoint slab region, no barrier)
#pragma unroll
    for (int mt = 0; mt < 2; ++mt)
#pragma unroll
        for (int r = 0; r < 16; ++r) {
            int crow = (r & 3) + 8 * (r >> 2) + rhi;
            Pls[(mt * 32 + crow) * PLSS + rA] = psum[mt][r];
        }
    const float* prow = Pls + lane * PLSS;
    f32x4 sv = {};
#pragma unroll
    for (int i = 0; i < 8; ++i) {
        f32x4 v = *(const f32x4*)(prow + i * 4);
        sv[0] += v[0]; sv[1] += v[1]; sv[2] += v[2]; sv[3] += v[3];
    }
    part2[(size_t)nb * M_ + rbase + lane] = sv[0] + sv[1] + sv[2] + sv[3];
}

// ---------------------------------------------------------------------------
// finish: rowsum from partials; out[n,0:V] = fp8decode(E8)*(1-c)/rowsum;
// out[n,V:] = copy part. 4 blocks per row (V quarter-split); copy in q==3.
template<bool E8P>
__global__ __launch_bounds__(256)
void k_finish(const u8* __restrict__ E8, const float* __restrict__ part2,
              const float* __restrict__ cvec, const float* __restrict__ attn,
              const int* __restrict__ ids, float* __restrict__ out)
{
    int n = blockIdx.y;
    int q = blockIdx.x;
    int tid = threadIdx.x;
    float c = cvec[n];
    float* row = out + (size_t)n * NC_;

    __shared__ float ws4[4];
    __shared__ float cp[CV_];
    if (q == 3 && tid < CV_) cp[tid] = 0.f;

    float s = 0.f;
    for (int p = tid; p < NB_; p += 256) s += part2[(size_t)p * M_ + n];
#pragma unroll
    for (int off = 32; off; off >>= 1) s += __shfl_down(s, off);
    if ((tid & 63) == 0) ws4[tid >> 6] = s;
    __syncthreads();
    float rowsum = ws4[0] + ws4[1] + ws4[2] + ws4[3];
    float sc = (1.f - c) / rowsum;

    if (q == 3 && tid < S_)
        atomicAdd(&cp[ids[tid * B_ + (n & (B_ - 1))]],
                  attn[(size_t)n * S_ + tid] * c);

    // V region split in units of 8 values: 6250 total, quarters of 1563
    int i0 = q * 1563;
    int i1 = min(i0 + 1563, V_ / 8);
    if (E8P) {
        const u8* e8 = E8 + (size_t)n * VP_;
        for (int i = i0 + tid; i < i1; i += 256) {
            u32x2 w = *(const u32x2*)(e8 + i * 8);
            f32x2 a0 = __builtin_amdgcn_cvt_pk_f32_fp8(w[0], false);
            f32x2 a1 = __builtin_amdgcn_cvt_pk_f32_fp8(w[0], true);
            f32x2 a2 = __builtin_amdgcn_cvt_pk_f32_fp8(w[1], false);
            f32x2 a3 = __builtin_amdgcn_cvt_pk_f32_fp8(w[1], true);
            f32x4 o0, o1;
            o0[0] = a0[0] * sc; o0[1] = a0[1] * sc;
            o0[2] = a1[0] * sc; o0[3] = a1[1] * sc;
            o1[0] = a2[0] * sc; o1[1] = a2[1] * sc;
            o1[2] = a3[0] * sc; o1[3] = a3[1] * sc;
            __builtin_nontemporal_store(o0, (f32x4*)(row + i * 8));
            __builtin_nontemporal_store(o1, (f32x4*)(row + i * 8 + 4));
        }
    } else {
        for (int i = i0 * 2 + tid; i < i1 * 2; i += 256) {
            f32x4 v = *(const f32x4*)(row + i * 4);
            v[0]*=sc; v[1]*=sc; v[2]*=sc; v[3]*=sc;
            *(f32x4*)(row + i * 4) = v;
        }
    }
    if (q == 3) {
        __syncthreads();
        if (tid < CV_) row[V_ + tid] = cp[tid];
    }
}

// ---------------------------------------------------------------------------
extern "C" void kernel_launch(void* const* d_in, const int* in_sizes, int n_in,
                              void* d_out, int out_size, void* d_ws, size_t ws_size,
                              hipStream_t stream)
{
    const float* hidden  = (const float*)d_in[0];
    const float* attn    = (const float*)d_in[1];
    const float* src_map = (const float*)d_in[2];
    const float* W       = (const float*)d_in[3];
    const float* bias    = (const float*)d_in[4];
    const float* w_copy  = (const float*)d_in[5];
    const float* b_copy  = (const float*)d_in[6];
    float* out = (float*)d_out;

    // workspace layout
    size_t off = 0;
    u8* Wt = (u8*)((char*)d_ws + off); off += (size_t)VP_ * K_;
    u8* Ab = (u8*)((char*)d_ws + off); off += (size_t)M_ * K_;
    float* cvec = (float*)((char*)d_ws + off); off += M_ * 4;
    int*   ids  = (int*)((char*)d_ws + off);   off += 16384;
    float* part2 = (float*)((char*)d_ws + off); off += (size_t)NB_ * M_ * 4;
    u8* E8 = (u8*)((char*)d_ws + off);
    bool e8p = (off + (size_t)M_ * VP_) <= ws_size;

    k_pre<<<WT_BLKS + PREP_BLKS + IDS_BLKS, 256, 0, stream>>>(
        W, Wt, hidden, w_copy, b_copy, Ab, cvec, src_map, ids);

    dim3 gg(NMT, NB_);
    dim3 gf(4, M_);
    if (e8p) {
        k_gemm_exp<true><<<gg, 256, 0, stream>>>(Ab, Wt, bias, out, E8, part2);
        k_finish<true><<<gf, 256, 0, stream>>>(E8, part2, cvec, attn, ids, out);
    } else {
        k_gemm_exp<false><<<gg, 256, 0, stream>>>(Ab, Wt, bias, out, E8, part2);
        k_finish<false><<<gf, 256, 0, stream>>>((const u8*)out, part2, cvec, attn, ids, out);
    }
}

// Round 15
// 331.408 us; speedup vs baseline: 1.5416x; 1.5416x over previous
//
#include <hip/hip_runtime.h>
#include <hip/hip_bf16.h>
#include <math.h>

// Problem constants
#define M_ 2048
#define K_ 1024
#define V_ 50000
#define VP_ 50048        // V padded to 128
#define CV_ 120
#define NC_ (V_ + CV_)   // 50120 out row stride
#define S_ 100
#define B_ 32
#define PAD_IDX_ 1

// GEMM tiling: block 256x128, 8 waves (4M x 2N), wave tile 64x64
// fp8 e4m3 operands, BK=64 (64 BYTES per row)
#define BM 256
#define BN 128
#define BK 64
#define NKT (K_ / BK)                   // 16 k-steps
#define NB_ (VP_ / BN)                  // 391 N-blocks
#define NMT (M_ / BM)                   // 8 M-blocks
#define NWG_ (NMT * NB_)                // 3128 = 8 * 391
#define WPX_ (NWG_ / 8)                 // 391 (exact)
#define BUFB 24576                      // BYTES per pipeline buf (A 16KB + B 8KB)
#define ELSB 80                         // Els row stride (BYTES)
#define PLSS 34                         // Pls row stride (floats)
#define PSLAB 8704                      // per-wave epilogue slab (Pls 64*34*4)
#define LN16 2.772588722239781f         // E stored as e/16 == exp(logit - ln16)

// merged pre-kernel block ranges
#define WT_BLKS (782 * 16)              // 12512 (64v x 64k tiles)
#define PREP_BLKS (M_ / 4)              // 512
#define IDS_BLKS (((S_ * B_) + 255) / 256) // 13

typedef float f32x2 __attribute__((ext_vector_type(2)));
typedef float f32x4 __attribute__((ext_vector_type(4)));
typedef float f32x16 __attribute__((ext_vector_type(16)));
typedef int i32x4 __attribute__((ext_vector_type(4)));
typedef int i32x8 __attribute__((ext_vector_type(8)));
typedef unsigned int u32x2 __attribute__((ext_vector_type(2)));
typedef unsigned short ushort;
typedef unsigned char u8;

__device__ __forceinline__ void async_copy16(const void* g, void* l) {
    __builtin_amdgcn_global_load_lds(
        (const __attribute__((address_space(1))) void*)g,
        (__attribute__((address_space(3))) void*)l, 16, 0, 0);
}
// quarter-wave conflict-free chunk swizzle (verified r4: conflicts -> 0)
#define SIG(row) (((row) >> 1) & 3)

// ---------------------------------------------------------------------------
// merged pre-pass: [0,WT_BLKS) W-transpose->fp8; [WT,+PREP) hidden->fp8 +
// copy gate; [+PREP,+IDS) one-hot -> ids.
__global__ __launch_bounds__(256)
void k_pre(const float* __restrict__ W, u8* __restrict__ Wt,
           const float* __restrict__ hidden, const float* __restrict__ w_copy,
           const float* __restrict__ b_copy, u8* __restrict__ Ab,
           float* __restrict__ cvec, const float* __restrict__ src_map,
           int* __restrict__ ids)
{
    int bx = blockIdx.x;
    int tid = threadIdx.x;
    if (bx < WT_BLKS) {
        // ---- W [K][V] fp32 -> Wt [VP][K] fp8 (64x64 tile transpose)
        __shared__ __align__(16) u8 t8[64][80];
        int v0 = (bx % 782) * 64;
        int k0 = (bx / 782) * 64;
        int kr = tid >> 4;          // 0..15
        int vq = tid & 15;
        int v4 = v0 + vq * 4;
#pragma unroll
        for (int i = 0; i < 4; ++i) {
            int k = k0 + kr + i * 16;
            f32x4 val = {};
            if (v4 < V_) val = __builtin_nontemporal_load(
                                   (const f32x4*)(W + (size_t)k * V_ + v4));
#pragma unroll
            for (int c = 0; c < 4; ++c) {
                int r = __builtin_amdgcn_cvt_pk_fp8_f32(val[c], 0.f, 0, 0);
                t8[vq * 4 + c][kr + i * 16] = (u8)r;
            }
        }
        __syncthreads();
        int vr = tid >> 2;          // 0..63
        int q  = tid & 3;           // 16B chunk of the 64B k-run
        i32x4 o = *(const i32x4*)(&t8[vr][q * 16]);
        *(i32x4*)(Wt + (size_t)(v0 + vr) * K_ + k0 + q * 16) = o;
    } else if (bx < WT_BLKS + PREP_BLKS) {
        // ---- hidden->fp8 + copy gate. 1 wave per row.
        int n = (bx - WT_BLKS) * 4 + (tid >> 6);
        int lane = tid & 63;
        const float* h = hidden + (size_t)n * K_;
        u8* arow = Ab + (size_t)n * K_;
        float s = 0.f;
#pragma unroll
        for (int g = 0; g < 2; ++g) {
            int gg = 2 * lane + g;            // granule 0..127 (8 elems)
            f32x4 a = *(const f32x4*)(h + gg * 8);
            f32x4 b = *(const f32x4*)(h + gg * 8 + 4);
            f32x4 wa = *(const f32x4*)(w_copy + gg * 8);
            f32x4 wb = *(const f32x4*)(w_copy + gg * 8 + 4);
            s += a[0]*wa[0] + a[1]*wa[1] + a[2]*wa[2] + a[3]*wa[3]
               + b[0]*wb[0] + b[1]*wb[1] + b[2]*wb[2] + b[3]*wb[3];
            int p0 = __builtin_amdgcn_cvt_pk_fp8_f32(a[0], a[1], 0, 0);
            p0 = __builtin_amdgcn_cvt_pk_fp8_f32(a[2], a[3], p0, 1);
            int p1 = __builtin_amdgcn_cvt_pk_fp8_f32(b[0], b[1], 0, 0);
            p1 = __builtin_amdgcn_cvt_pk_fp8_f32(b[2], b[3], p1, 1);
            u32x2 pk; pk[0] = (unsigned)p0; pk[1] = (unsigned)p1;
            *(u32x2*)(arow + gg * 8) = pk;
        }
#pragma unroll
        for (int off = 32; off; off >>= 1) s += __shfl_down(s, off);
        if (lane == 0) cvec[n] = 1.f / (1.f + __expf(-(s + b_copy[0])));
    } else {
        // ---- one-hot src_map -> integer ids [S*B]
        int i = (bx - WT_BLKS - PREP_BLKS) * 256 + tid;
        if (i < S_ * B_) {
            const float* r = src_map + (size_t)i * CV_;
            int id = 0;
            for (int v = 0; v < CV_; ++v)
                if (r[v] > 0.5f) { id = v; break; }
            ids[i] = id;
        }
    }
}

// ---------------------------------------------------------------------------
// GEMM (MX-fp8): e' = exp(A.Wt^T + b - ln16) (PAD col->0); fp8 E store;
// 2 row-partials per (block,row). 512 threads, 8 waves of 64x64 tiles,
// 3-buf pipeline, counted vmcnt(3), raw s_barrier, setprio, 2-sub-phase body.
template<bool E8P>
__global__ __launch_bounds__(512, 4)
void k_gemm_exp(const u8* __restrict__ A, const u8* __restrict__ Bt,
                const float* __restrict__ bias, float* __restrict__ out,
                u8* __restrict__ E8, float* __restrict__ part2)
{
    __shared__ __align__(16) u8 lds8[3 * BUFB];   // 72 KB

    const int tid  = threadIdx.x;
    const int lane = tid & 63;
    const int wid  = tid >> 6;    // 0..7
    const int wm   = wid >> 1;    // 0..3 (M)
    const int wn   = wid & 1;     // 0..1 (N)

    // bijective XCD swizzle: 3128 = 8 * 391
    int orig = blockIdx.y * NMT + blockIdx.x;
    int nid  = (orig & 7) * WPX_ + (orig >> 3);
    const int m0 = (nid & 7) * BM;    // m fastest within an XCD's chunk
    const int nb = nid >> 3;
    const int n0 = nb * BN;

    f32x16 acc[2][2] = {};

    // A tile: 256 rows x 64B = 1024 granules (2/thread); B: 128 rows = 512 (1/thread)
#define STAGE_A(d, kt)                                                        \
    do {                                                                      \
        _Pragma("unroll")                                                     \
        for (int j = 0; j < 2; ++j) {                                         \
            int g = j * 512 + tid; int row = g >> 2;                          \
            int ch = (g & 3) ^ SIG(row);                                      \
            async_copy16(A + (size_t)(m0 + row) * K_ + (kt) * BK + ch * 16,   \
                         &lds8[(d) * BUFB + g * 16]);                         \
        }                                                                     \
    } while (0)
#define STAGE_B(d, kt)                                                        \
    do {                                                                      \
        int g = tid; int row = g >> 2;                                        \
        int ch = (g & 3) ^ SIG(row);                                          \
        async_copy16(Bt + (size_t)(n0 + row) * K_ + (kt) * BK + ch * 16,      \
                     &lds8[(d) * BUFB + 16384 + g * 16]);                     \
    } while (0)

    STAGE_A(0, 0); STAGE_B(0, 0);
    STAGE_A(1, 1); STAGE_B(1, 1);

    // 32x32x64 f8f6f4 fragment: row = tile + (lane&31); lane holds 32 k-bytes
    // at k = (lane>>5)*32 (two 16B chunks, SIG-swizzled like staging).
    const int rA  = lane & 31;
    const int kb  = lane >> 5;
    const int sig = (rA >> 1) & 3;

#pragma unroll
    for (int kt = 0; kt < NKT; ++kt) {
        const int cur = kt % 3;
        const int nxt = (kt + 2) % 3;
        __builtin_amdgcn_sched_barrier(0);
        if (kt < NKT - 1) asm volatile("s_waitcnt vmcnt(3)" ::: "memory");
        else              asm volatile("s_waitcnt vmcnt(0)" ::: "memory");
        __builtin_amdgcn_s_barrier();           // S_kt landed; buf(kt-1) reads done
        __builtin_amdgcn_sched_barrier(0);
        const u8* bufA = &lds8[cur * BUFB];
        const u8* bufB = bufA + 16384;
        i32x8 fa[2], fb[2];
        // ---- sub-phase 1: fa + fb[0] reads, A-stage, 2 MFMA
#pragma unroll
        for (int mt = 0; mt < 2; ++mt) {
            int ro = (wm * 64 + mt * 32 + rA) * 64;
            i32x4 lo = *(const i32x4*)(bufA + ro + (((2 * kb + 0) ^ sig) << 4));
            i32x4 hi = *(const i32x4*)(bufA + ro + (((2 * kb + 1) ^ sig) << 4));
            fa[mt] = __builtin_shufflevector(lo, hi, 0, 1, 2, 3, 4, 5, 6, 7);
        }
        {
            int ro = (wn * 64 + rA) * 64;
            i32x4 lo = *(const i32x4*)(bufB + ro + (((2 * kb + 0) ^ sig) << 4));
            i32x4 hi = *(const i32x4*)(bufB + ro + (((2 * kb + 1) ^ sig) << 4));
            fb[0] = __builtin_shufflevector(lo, hi, 0, 1, 2, 3, 4, 5, 6, 7);
        }
        if (kt < NKT - 2) STAGE_A(nxt, kt + 2);
        __builtin_amdgcn_s_setprio(1);
#pragma unroll
        for (int mt = 0; mt < 2; ++mt)
            acc[mt][0] = __builtin_amdgcn_mfma_scale_f32_32x32x64_f8f6f4(
                fa[mt], fb[0], acc[mt][0], 0, 0, 0, 127, 0, 127);
        __builtin_amdgcn_s_setprio(0);
        __builtin_amdgcn_sched_barrier(0);      // keep sub-phase 2 below
        // ---- sub-phase 2: fb[1] reads, B-stage, 2 MFMA
        {
            int ro = (wn * 64 + 32 + rA) * 64;
            i32x4 lo = *(const i32x4*)(bufB + ro + (((2 * kb + 0) ^ sig) << 4));
            i32x4 hi = *(const i32x4*)(bufB + ro + (((2 * kb + 1) ^ sig) << 4));
            fb[1] = __builtin_shufflevector(lo, hi, 0, 1, 2, 3, 4, 5, 6, 7);
        }
        if (kt < NKT - 2) STAGE_B(nxt, kt + 2);
        __builtin_amdgcn_s_setprio(1);
#pragma unroll
        for (int mt = 0; mt < 2; ++mt)
            acc[mt][1] = __builtin_amdgcn_mfma_scale_f32_32x32x64_f8f6f4(
                fa[mt], fb[1], acc[mt][1], 0, 0, 0, 127, 0, 127);
        __builtin_amdgcn_s_setprio(0);
    }
#undef STAGE_A
#undef STAGE_B

    __builtin_amdgcn_s_barrier();   // main loop fully done before LDS reuse

    // epilogue: e' = exp(acc + bias - ln16); fp8-at-write Els staging (bytes),
    // 4-pass coalesced 16B E8 stores, then per-wave Pls reduce (slab reuse).
    // C/D layout (verified m74/m101): col = lane&31, row = (r&3)+8*(r>>2)+4*(lane>>5)
    const int rbase = m0 + wm * 64;
    const int cbase = n0 + wn * 64;
    const int rhi   = (lane >> 5) * 4;
    float psum[2][16];
#pragma unroll
    for (int mt = 0; mt < 2; ++mt)
#pragma unroll
        for (int r = 0; r < 16; ++r) psum[mt][r] = 0.f;
    u8* Els8 = lds8 + wid * PSLAB;
    float* Pls = (float*)(lds8 + wid * PSLAB);   // sequential reuse of slab
#pragma unroll
    for (int nt = 0; nt < 2; ++nt) {
        int gcol = cbase + nt * 32 + rA;
        bool live = (gcol < V_) && (gcol != PAD_IDX_);
        float bln = ((gcol < V_) ? bias[gcol] : 0.f) - LN16;
#pragma unroll
        for (int mt = 0; mt < 2; ++mt) {
#pragma unroll
            for (int r = 0; r < 16; ++r) {
                int crow = (r & 3) + 8 * (r >> 2) + rhi;
                float e = live ? __expf(acc[mt][nt][r] + bln) : 0.f;
                psum[mt][r] += e;
                if (E8P) {
                    Els8[(mt * 32 + crow) * ELSB + nt * 32 + rA] =
                        (u8)__builtin_amdgcn_cvt_pk_fp8_f32(e, 0.f, 0, 0);
                } else {
                    int grow = rbase + mt * 32 + crow;
                    if (gcol < V_) out[(size_t)grow * NC_ + gcol] = e;
                }
            }
        }
    }
    if (E8P) {
        // 4 passes: 16 rows x 64B coalesced segments per pass
#pragma unroll
        for (int p = 0; p < 4; ++p) {
            int row_l = p * 16 + (lane >> 2);
            int g = lane & 3;
            i32x4 v = *(const i32x4*)(&Els8[row_l * ELSB + g * 16]);
            *(i32x4*)&E8[(size_t)(rbase + row_l) * VP_ + cbase + g * 16] = v;
        }
    }
    __builtin_amdgcn_sched_barrier(0);   // order Els reads before Pls overwrite
    // per-wave Pls transpose reduce (same-wave in-order DS, no barrier)
#pragma unroll
    for (int mt = 0; mt < 2; ++mt)
#pragma unroll
        for (int r = 0; r < 16; ++r) {
            int crow = (r & 3) + 8 * (r >> 2) + rhi;
            Pls[(mt * 32 + crow) * PLSS + rA] = psum[mt][r];
        }
    const float* prow = Pls + lane * PLSS;
    f32x4 sv = {};
#pragma unroll
    for (int i = 0; i < 8; ++i) {
        f32x4 v = *(const f32x4*)(prow + i * 4);
        sv[0] += v[0]; sv[1] += v[1]; sv[2] += v[2]; sv[3] += v[3];
    }
    part2[((size_t)nb * 2 + wn) * M_ + rbase + lane] = sv[0] + sv[1] + sv[2] + sv[3];
}

// ---------------------------------------------------------------------------
// finish: rowsum from partials (2*NB_ per row); out[n,0:V] =
// fp8decode(E8)*(1-c)/rowsum; out[n,V:] = copy part. 4 blocks per row.
template<bool E8P>
__global__ __launch_bounds__(256)
void k_finish(const u8* __restrict__ E8, const float* __restrict__ part2,
              const float* __restrict__ cvec, const float* __restrict__ attn,
              const int* __restrict__ ids, float* __restrict__ out)
{
    int n = blockIdx.y;
    int q = blockIdx.x;
    int tid = threadIdx.x;
    float c = cvec[n];
    float* row = out + (size_t)n * NC_;

    __shared__ float ws4[4];
    __shared__ float cp[CV_];
    if (q == 3 && tid < CV_) cp[tid] = 0.f;

    float s = 0.f;
    for (int p = tid; p < 2 * NB_; p += 256) s += part2[(size_t)p * M_ + n];
#pragma unroll
    for (int off = 32; off; off >>= 1) s += __shfl_down(s, off);
    if ((tid & 63) == 0) ws4[tid >> 6] = s;
    __syncthreads();
    float rowsum = ws4[0] + ws4[1] + ws4[2] + ws4[3];
    float sc = (1.f - c) / rowsum;

    if (q == 3 && tid < S_)
        atomicAdd(&cp[ids[tid * B_ + (n & (B_ - 1))]],
                  attn[(size_t)n * S_ + tid] * c);

    // V region split in units of 8 values: 6250 total, quarters of 1563
    int i0 = q * 1563;
    int i1 = min(i0 + 1563, V_ / 8);
    if (E8P) {
        const u8* e8 = E8 + (size_t)n * VP_;
        for (int i = i0 + tid; i < i1; i += 256) {
            u32x2 w = *(const u32x2*)(e8 + i * 8);
            f32x2 a0 = __builtin_amdgcn_cvt_pk_f32_fp8(w[0], false);
            f32x2 a1 = __builtin_amdgcn_cvt_pk_f32_fp8(w[0], true);
            f32x2 a2 = __builtin_amdgcn_cvt_pk_f32_fp8(w[1], false);
            f32x2 a3 = __builtin_amdgcn_cvt_pk_f32_fp8(w[1], true);
            f32x4 o0, o1;
            o0[0] = a0[0] * sc; o0[1] = a0[1] * sc;
            o0[2] = a1[0] * sc; o0[3] = a1[1] * sc;
            o1[0] = a2[0] * sc; o1[1] = a2[1] * sc;
            o1[2] = a3[0] * sc; o1[3] = a3[1] * sc;
            __builtin_nontemporal_store(o0, (f32x4*)(row + i * 8));
            __builtin_nontemporal_store(o1, (f32x4*)(row + i * 8 + 4));
        }
    } else {
        for (int i = i0 * 2 + tid; i < i1 * 2; i += 256) {
            f32x4 v = *(const f32x4*)(row + i * 4);
            v[0]*=sc; v[1]*=sc; v[2]*=sc; v[3]*=sc;
            *(f32x4*)(row + i * 4) = v;
        }
    }
    if (q == 3) {
        __syncthreads();
        if (tid < CV_) row[V_ + tid] = cp[tid];
    }
}

// ---------------------------------------------------------------------------
extern "C" void kernel_launch(void* const* d_in, const int* in_sizes, int n_in,
                              void* d_out, int out_size, void* d_ws, size_t ws_size,
                              hipStream_t stream)
{
    const float* hidden  = (const float*)d_in[0];
    const float* attn    = (const float*)d_in[1];
    const float* src_map = (const float*)d_in[2];
    const float* W       = (const float*)d_in[3];
    const float* bias    = (const float*)d_in[4];
    const float* w_copy  = (const float*)d_in[5];
    const float* b_copy  = (const float*)d_in[6];
    float* out = (float*)d_out;

    // workspace layout
    size_t off = 0;
    u8* Wt = (u8*)((char*)d_ws + off); off += (size_t)VP_ * K_;
    u8* Ab = (u8*)((char*)d_ws + off); off += (size_t)M_ * K_;
    float* cvec = (float*)((char*)d_ws + off); off += M_ * 4;
    int*   ids  = (int*)((char*)d_ws + off);   off += 16384;
    float* part2 = (float*)((char*)d_ws + off); off += (size_t)NB_ * 2 * M_ * 4;
    u8* E8 = (u8*)((char*)d_ws + off);
    bool e8p = (off + (size_t)M_ * VP_) <= ws_size;

    k_pre<<<WT_BLKS + PREP_BLKS + IDS_BLKS, 256, 0, stream>>>(
        W, Wt, hidden, w_copy, b_copy, Ab, cvec, src_map, ids);

    dim3 gg(NMT, NB_);
    dim3 gf(4, M_);
    if (e8p) {
        k_gemm_exp<true><<<gg, 512, 0, stream>>>(Ab, Wt, bias, out, E8, part2);
        k_finish<true><<<gf, 256, 0, stream>>>(E8, part2, cvec, attn, ids, out);
    } else {
        k_gemm_exp<false><<<gg, 512, 0, stream>>>(Ab, Wt, bias, out, E8, part2);
        k_finish<false><<<gf, 256, 0, stream>>>((const u8*)out, part2, cvec, attn, ids, out);
    }
}